// Round 5
// baseline (92.124 us; speedup 1.0000x reference)
//
#include <hip/hip_runtime.h>
#include <math.h>

#define EMBED 768
#define SEQ   2048
#define NB    8
#define SQRT_E 27.712812921102035f   // sqrt(768), folded into Wq at split time

typedef short  short8 __attribute__((ext_vector_type(8)));
typedef float  f32x4  __attribute__((ext_vector_type(4)));

// ws layout (ushort element offsets)
#define WHI_OFF  0u
#define WLO_OFF  147456u
#define QHI_OFF  294912u
#define QLO_OFF  (294912u + 1u*1048576u)
#define KHI_OFF  (294912u + 2u*1048576u)
#define KLO_OFF  (294912u + 3u*1048576u)
#define VT_OFF   (294912u + 4u*1048576u)

__device__ __forceinline__ ushort f2bf(float f) {          // round-to-nearest
    unsigned u = __float_as_uint(f);
    return (ushort)((u + 0x7FFFu + ((u >> 16) & 1u)) >> 16);
}
__device__ __forceinline__ ushort f2bf_trunc(float f) {    // cheap, for lo part
    return (ushort)(__float_as_uint(f) >> 16);
}
__device__ __forceinline__ float bf2f(ushort h) {
    return __uint_as_float(((unsigned)h) << 16);
}

// ---------------------------------------------------------------------------
// Kernel 0: split W into bf16 hi/lo.  rows: [0,64)=Wq*sqrt(E), [64,128)=Wk,
// [128,192)=Wv.  w_hi/w_lo are [192][768] bf16 row-major.
// ---------------------------------------------------------------------------
__global__ __launch_bounds__(256)
void split_w_kernel(const float* __restrict__ Wq, const float* __restrict__ Wk,
                    const float* __restrict__ Wv,
                    ushort* __restrict__ w_hi, ushort* __restrict__ w_lo)
{
    int idx = blockIdx.x * 256 + threadIdx.x;
    if (idx >= 192 * EMBED) return;
    int row = idx / EMBED, e = idx - row * EMBED;
    float f;
    if (row < 64)       f = Wq[row * EMBED + e] * SQRT_E;
    else if (row < 128) f = Wk[(row - 64) * EMBED + e];
    else                f = Wv[(row - 128) * EMBED + e];
    ushort hi = f2bf(f);
    w_hi[idx] = hi;
    w_lo[idx] = f2bf_trunc(f - bf2f(hi));
}

// ---------------------------------------------------------------------------
// Kernel 1: QKV projection, LDS-staged, register prefetch across barriers.
// BM=32 (grid 512) so LDS=55KB -> 2 blocks/CU co-resident: one block's
// compute covers the other's barrier drain.  Block 256 thr = 4 waves
// (wm in {0,1}: 16-row half; ch in {0,1}: col parity); wave = 16 rows x
// 96 cols (6 interleaved n-tiles), K-chunk 64 (12 chunks), 28 MFMA/chunk.
// q/k cols: 3-product split-bf16; v cols single product (no W-lo staged).
// ---------------------------------------------------------------------------
__global__ __launch_bounds__(256)
void proj_kernel(const float* __restrict__ x,
                 const ushort* __restrict__ w_hi, const ushort* __restrict__ w_lo,
                 ushort* __restrict__ q_hi, ushort* __restrict__ q_lo,
                 ushort* __restrict__ k_hi, ushort* __restrict__ k_lo,
                 ushort* __restrict__ v_t)
{
    __shared__ __align__(16) ushort xa_hi[32][72], xa_lo[32][72];
    __shared__ __align__(16) ushort wb_hi[192][72];
    __shared__ __align__(16) ushort wb_lo[128][72];

    const int t    = threadIdx.x;
    const int lane = t & 63;
    const int wid  = t >> 6;
    const int wm   = wid >> 1;      // 0,1: rows wm*16 .. +15
    const int ch   = wid & 1;       // col parity (even/odd n-tiles)
    const int ln   = lane & 15;
    const int kg   = lane >> 4;     // 0..3
    const int row0 = blockIdx.x * 32;

    const int srow = t >> 3;            // 0..31 (x staging row)
    const int scol = (t & 7) * 8;       // x staging col (8 floats)
    const int wrow = t >> 2;            // 0..63 (W staging row group)
    const int wcol = (t & 3) * 16;      // W staging col (16 elems)

    // prefetch registers
    float4 xr0, xr1;
    short8 wh0, wh1, wh2, wh3, wh4, wh5;
    short8 wl0, wl1, wl2, wl3;

#define LOAD_CHUNK(e0) do {                                                     \
        const float*  xp_ = x + (size_t)(row0 + srow) * EMBED + (e0) + scol;    \
        xr0 = *(const float4*)xp_;  xr1 = *(const float4*)(xp_ + 4);            \
        const ushort* whp_ = w_hi + (size_t)wrow * EMBED + (e0) + wcol;         \
        wh0 = *(const short8*)whp_;                                             \
        wh1 = *(const short8*)(whp_ + 8);                                       \
        wh2 = *(const short8*)(whp_ + 64 * EMBED);                              \
        wh3 = *(const short8*)(whp_ + 64 * EMBED + 8);                          \
        wh4 = *(const short8*)(whp_ + 128 * EMBED);                             \
        wh5 = *(const short8*)(whp_ + 128 * EMBED + 8);                         \
        const ushort* wlp_ = w_lo + (size_t)wrow * EMBED + (e0) + wcol;         \
        wl0 = *(const short8*)wlp_;                                             \
        wl1 = *(const short8*)(wlp_ + 8);                                       \
        wl2 = *(const short8*)(wlp_ + 64 * EMBED);                              \
        wl3 = *(const short8*)(wlp_ + 64 * EMBED + 8);                          \
    } while (0)

    const f32x4 vzero = {0.f, 0.f, 0.f, 0.f};
    f32x4 acc[6];
#pragma unroll
    for (int j = 0; j < 6; ++j) acc[j] = vzero;

    LOAD_CHUNK(0);

    for (int c = 0; c < 12; ++c) {
        if (c) __syncthreads();          // all waves done reading prev chunk
        // ---- stage regs -> LDS (x converted fp32 -> bf16 hi/lo) ----
        {
            const float fv[8] = {xr0.x, xr0.y, xr0.z, xr0.w,
                                 xr1.x, xr1.y, xr1.z, xr1.w};
            short8 h0, l0;
#pragma unroll
            for (int i = 0; i < 8; ++i) {
                ushort h = f2bf(fv[i]);
                h0[i] = (short)h;
                l0[i] = (short)f2bf_trunc(fv[i] - bf2f(h));
            }
            *(short8*)&xa_hi[srow][scol] = h0;
            *(short8*)&xa_lo[srow][scol] = l0;
            *(short8*)&wb_hi[wrow][wcol]           = wh0;
            *(short8*)&wb_hi[wrow][wcol + 8]       = wh1;
            *(short8*)&wb_hi[wrow + 64][wcol]      = wh2;
            *(short8*)&wb_hi[wrow + 64][wcol + 8]  = wh3;
            *(short8*)&wb_hi[wrow + 128][wcol]     = wh4;
            *(short8*)&wb_hi[wrow + 128][wcol + 8] = wh5;
            *(short8*)&wb_lo[wrow][wcol]           = wl0;
            *(short8*)&wb_lo[wrow][wcol + 8]       = wl1;
            *(short8*)&wb_lo[wrow + 64][wcol]      = wl2;
            *(short8*)&wb_lo[wrow + 64][wcol + 8]  = wl3;
        }
        __syncthreads();
        // ---- prefetch next chunk (overlaps compute below) ----
        if (c < 11) LOAD_CHUNK((c + 1) * 64);

        // ---- fragments + MFMA ----
        short8 ah[2], al[2];
#pragma unroll
        for (int ks = 0; ks < 2; ++ks) {
            ah[ks] = *(const short8*)&xa_hi[wm * 16 + ln][ks * 32 + kg * 8];
            al[ks] = *(const short8*)&xa_lo[wm * 16 + ln][ks * 32 + kg * 8];
        }
#pragma unroll
        for (int j = 0; j < 6; ++j) {
            const int ntg = 2 * j + ch;
#pragma unroll
            for (int ks = 0; ks < 2; ++ks) {
                short8 bh = *(const short8*)&wb_hi[ntg * 16 + ln][ks * 32 + kg * 8];
                acc[j] = __builtin_amdgcn_mfma_f32_16x16x32_bf16(ah[ks], bh, acc[j], 0, 0, 0);
                if (j < 4) {   // qk tiles (ntg < 8): split correction terms
                    short8 bl = *(const short8*)&wb_lo[ntg * 16 + ln][ks * 32 + kg * 8];
                    acc[j] = __builtin_amdgcn_mfma_f32_16x16x32_bf16(ah[ks], bl, acc[j], 0, 0, 0);
                    acc[j] = __builtin_amdgcn_mfma_f32_16x16x32_bf16(al[ks], bh, acc[j], 0, 0, 0);
                }
            }
        }
    }
#undef LOAD_CHUNK

    // ---- epilogue: C layout col=lane&15, row=(lane>>4)*4+reg ----
    {
        const int rbase = row0 + wm * 16 + kg * 4;
#pragma unroll
        for (int j = 0; j < 6; ++j) {
            const int ntg = 2 * j + ch;
            const int col = ntg * 16 + ln;
#pragma unroll
            for (int r = 0; r < 4; ++r) {
                int rg = rbase + r;
                int b = rg >> 11, s = rg & 2047;
                size_t rowoff = ((size_t)b * SEQ + s) * 64;
                float val = acc[j][r];
                if (col < 64) {
                    ushort h = f2bf(val);
                    q_hi[rowoff + col] = h;
                    q_lo[rowoff + col] = f2bf_trunc(val - bf2f(h));
                } else if (col < 128) {
                    ushort h = f2bf(val);
                    k_hi[rowoff + (col - 64)] = h;
                    k_lo[rowoff + (col - 64)] = f2bf_trunc(val - bf2f(h));
                } else {
                    v_t[((size_t)b * 64 + (col - 128)) * SEQ + s] = f2bf(val);
                }
            }
        }
    }
}

// ---------------------------------------------------------------------------
// Kernel 2: causal flash attention, k-split 4, 2-deep register pipeline.
// Block 256 thr = 4 waves on the SAME 16-row q-tile; wave w does k-tiles
// jt = w, w+4, ...; merge partials once via LDS.  Swapped QK^T (lane owns
// query-column ln).  K/V read from global (L2-resident, batch pinned to
// XCD via bid&7).  Two named register sets A/B double-buffer the next
// tile's 12 loads so L2 latency hides under the other tile's compute.
// No VGPR cap (R4's (256,4) -> 60 VGPR serialized all loads).
// ---------------------------------------------------------------------------
__global__ __launch_bounds__(256)
void attn_kernel(const ushort* __restrict__ q_hi, const ushort* __restrict__ q_lo,
                 const ushort* __restrict__ k_hi, const ushort* __restrict__ k_lo,
                 const ushort* __restrict__ v_t, float* __restrict__ out)
{
    __shared__ __align__(16) ushort pT[4][16][72];
    __shared__ float obuf[3][16][72];
    __shared__ float mbuf[3][16], lbuf[3][16];

    const int t    = threadIdx.x;
    const int lane = t & 63;
    const int w    = t >> 6;          // k-split quarter 0..3
    const int ln   = lane & 15;
    const int kg   = lane >> 4;       // 0..3
    const int b    = blockIdx.x & 7;  // batch pinned to XCD
    const int qt   = 127 - (blockIdx.x >> 3);   // longest first
    const int r0   = qt * 16;

    const ushort* qhb = q_hi + (size_t)b * SEQ * 64;
    const ushort* qlb = q_lo + (size_t)b * SEQ * 64;
    const ushort* khb = k_hi + (size_t)b * SEQ * 64;
    const ushort* klb = k_lo + (size_t)b * SEQ * 64;
    const ushort* vtb = v_t + (size_t)b * 64 * SEQ;
    float*        ob  = out + (size_t)b * SEQ * 64;

    // Q fragments (hi/lo, 2 k-steps) in registers for the whole tile
    short8 qh[2], ql[2];
#pragma unroll
    for (int ks = 0; ks < 2; ++ks) {
        size_t off = (size_t)(r0 + ln) * 64 + ks * 32 + kg * 8;
        qh[ks] = *(const short8*)(qhb + off);
        ql[ks] = *(const short8*)(qlb + off);
    }

    const f32x4 vzero = {0.f, 0.f, 0.f, 0.f};
    f32x4 o[4];
#pragma unroll
    for (int i = 0; i < 4; ++i) o[i] = vzero;
    float m_run = -INFINITY, l_run = 0.f;
    const int qrow = r0 + ln;
    const int nt = qt / 4 + 1;        // causal 64-key tiles for this q-tile

    // ---- tile load / process as inlined lambdas over named reg sets ----
    auto ld_tile = [&](short8 (&kfh)[4][2], short8 (&kfl)[4][2],
                       short8 (&vf)[4][2], int jt) {
        const size_t kbase = (size_t)jt * 64 * 64;
#pragma unroll
        for (int ct = 0; ct < 4; ++ct) {
            size_t off = kbase + (size_t)(ct * 16 + ln) * 64 + kg * 8;
            kfh[ct][0] = *(const short8*)(khb + off);
            kfh[ct][1] = *(const short8*)(khb + off + 32);
            kfl[ct][0] = *(const short8*)(klb + off);
            kfl[ct][1] = *(const short8*)(klb + off + 32);
        }
#pragma unroll
        for (int ht = 0; ht < 4; ++ht) {
            size_t voff = (size_t)(ht * 16 + ln) * SEQ + jt * 64 + kg * 8;
            vf[ht][0] = *(const short8*)(vtb + voff);
            vf[ht][1] = *(const short8*)(vtb + voff + 32);
        }
    };

    auto process = [&](short8 (&kfh)[4][2], short8 (&kfl)[4][2],
                       short8 (&vf)[4][2], int jt) {
        const int j0 = jt * 64;
        // QK^T (swapped): sacc[ct][r] = score[key=j0+ct*16+kg*4+r][q=ln]
        f32x4 sacc[4];
#pragma unroll
        for (int ct = 0; ct < 4; ++ct) sacc[ct] = vzero;
#pragma unroll
        for (int ct = 0; ct < 4; ++ct) {
#pragma unroll
            for (int ks = 0; ks < 2; ++ks) {
                sacc[ct] = __builtin_amdgcn_mfma_f32_16x16x32_bf16(kfh[ct][ks], qh[ks], sacc[ct], 0, 0, 0);
                sacc[ct] = __builtin_amdgcn_mfma_f32_16x16x32_bf16(kfh[ct][ks], ql[ks], sacc[ct], 0, 0, 0);
                sacc[ct] = __builtin_amdgcn_mfma_f32_16x16x32_bf16(kfl[ct][ks], qh[ks], sacc[ct], 0, 0, 0);
            }
        }
        // causal mask (diagonal tile only)
        if (jt == nt - 1) {
#pragma unroll
            for (int ct = 0; ct < 4; ++ct) {
                int kb0 = j0 + ct * 16 + kg * 4;
#pragma unroll
                for (int r = 0; r < 4; ++r)
                    if (kb0 + r > qrow) sacc[ct][r] = -1e30f;
            }
        }
        // online softmax for query ln (16 local + 2 shfl)
        float mt_ = fmaxf(fmaxf(fmaxf(sacc[0][0], sacc[0][1]), fmaxf(sacc[0][2], sacc[0][3])),
                          fmaxf(fmaxf(sacc[1][0], sacc[1][1]), fmaxf(sacc[1][2], sacc[1][3])));
        float mt2 = fmaxf(fmaxf(fmaxf(sacc[2][0], sacc[2][1]), fmaxf(sacc[2][2], sacc[2][3])),
                          fmaxf(fmaxf(sacc[3][0], sacc[3][1]), fmaxf(sacc[3][2], sacc[3][3])));
        mt_ = fmaxf(mt_, mt2);
        mt_ = fmaxf(mt_, __shfl_xor(mt_, 16));
        mt_ = fmaxf(mt_, __shfl_xor(mt_, 32));
        float mn   = fmaxf(m_run, mt_);
        float corr = __expf(m_run - mn);     // 0 on first tile
        float p[4][4];
        float lt = 0.f;
#pragma unroll
        for (int ct = 0; ct < 4; ++ct)
#pragma unroll
            for (int r = 0; r < 4; ++r) {
                p[ct][r] = __expf(sacc[ct][r] - mn);
                lt += p[ct][r];
            }
        lt += __shfl_xor(lt, 16);
        lt += __shfl_xor(lt, 32);
        m_run = mn;
        l_run = l_run * corr + lt;

        // P -> per-wave LDS (bf16, packed u32 stores)
#pragma unroll
        for (int ct = 0; ct < 4; ++ct) {
            uint u0 = (uint)f2bf(p[ct][0]) | ((uint)f2bf(p[ct][1]) << 16);
            uint u1 = (uint)f2bf(p[ct][2]) | ((uint)f2bf(p[ct][3]) << 16);
            *(uint*)&pT[w][ln][ct * 16 + kg * 4]     = u0;
            *(uint*)&pT[w][ln][ct * 16 + kg * 4 + 2] = u1;
        }
        // rescale O (rows are q = kg*4+r -> broadcast corr)
        float corrq[4];
#pragma unroll
        for (int r = 0; r < 4; ++r) corrq[r] = __shfl(corr, kg * 4 + r);
#pragma unroll
        for (int ht = 0; ht < 4; ++ht)
#pragma unroll
            for (int r = 0; r < 4; ++r) o[ht][r] *= corrq[r];
        // PV: o[q][h] += P[q][key] * V[key][h]
#pragma unroll
        for (int ks = 0; ks < 2; ++ks) {
            short8 pa = *(const short8*)&pT[w][ln][ks * 32 + kg * 8];
#pragma unroll
            for (int ht = 0; ht < 4; ++ht)
                o[ht] = __builtin_amdgcn_mfma_f32_16x16x32_bf16(pa, vf[ht][ks], o[ht], 0, 0, 0);
        }
    };

    // ---- 2-deep pipelined k-loop over this wave's quarter ----
    short8 kfhA[4][2], kflA[4][2], vfA[4][2];
    short8 kfhB[4][2], kflB[4][2], vfB[4][2];
    const int cnt = (nt - w + 3) >> 2;   // tiles this wave handles
    if (cnt > 0) ld_tile(kfhA, kflA, vfA, w);
    if (cnt > 1) ld_tile(kfhB, kflB, vfB, w + 4);
    for (int it = 0; it < cnt; it += 2) {
        const int jtA = w + it * 4;
        process(kfhA, kflA, vfA, jtA);
        if (it + 2 < cnt) ld_tile(kfhA, kflA, vfA, jtA + 8);
        if (it + 1 < cnt) {
            process(kfhB, kflB, vfB, jtA + 4);
            if (it + 3 < cnt) ld_tile(kfhB, kflB, vfB, jtA + 12);
        }
    }

    // ---- merge the 4 k-split partials ----
    if (w > 0) {
#pragma unroll
        for (int ht = 0; ht < 4; ++ht)
#pragma unroll
            for (int r = 0; r < 4; ++r)
                obuf[w - 1][kg * 4 + r][ht * 16 + ln] = o[ht][r];
        if (kg == 0) { mbuf[w - 1][ln] = m_run; lbuf[w - 1][ln] = l_run; }
    }
    __syncthreads();
    if (w == 0) {
        float m1 = mbuf[0][ln], m2 = mbuf[1][ln], m3 = mbuf[2][ln];
        float mm = fmaxf(fmaxf(m_run, m1), fmaxf(m2, m3));
        float c0 = __expf(m_run - mm);
        float c1 = __expf(m1 - mm);
        float c2 = __expf(m2 - mm);
        float c3 = __expf(m3 - mm);
        float li = l_run * c0 + lbuf[0][ln] * c1 + lbuf[1][ln] * c2 + lbuf[2][ln] * c3;
        float inv = 1.0f / li;
        float c0q[4], c1q[4], c2q[4], c3q[4], ivq[4];
#pragma unroll
        for (int r = 0; r < 4; ++r) {
            int src = kg * 4 + r;
            c0q[r] = __shfl(c0, src);
            c1q[r] = __shfl(c1, src);
            c2q[r] = __shfl(c2, src);
            c3q[r] = __shfl(c3, src);
            ivq[r] = __shfl(inv, src);
        }
#pragma unroll
        for (int ht = 0; ht < 4; ++ht)
#pragma unroll
            for (int r = 0; r < 4; ++r) {
                float val = o[ht][r] * c0q[r]
                          + obuf[0][kg * 4 + r][ht * 16 + ln] * c1q[r]
                          + obuf[1][kg * 4 + r][ht * 16 + ln] * c2q[r]
                          + obuf[2][kg * 4 + r][ht * 16 + ln] * c3q[r];
                ob[(size_t)(r0 + kg * 4 + r) * 64 + ht * 16 + ln] = val * ivq[r];
            }
    }
}

// ---------------------------------------------------------------------------
extern "C" void kernel_launch(void* const* d_in, const int* in_sizes, int n_in,
                              void* d_out, int out_size, void* d_ws, size_t ws_size,
                              hipStream_t stream)
{
    const float* x  = (const float*)d_in[0];
    const float* Wq = (const float*)d_in[1];
    const float* Wk = (const float*)d_in[2];
    const float* Wv = (const float*)d_in[3];
    float* out = (float*)d_out;

    ushort* ws = (ushort*)d_ws;
    ushort* w_hi = ws + WHI_OFF;
    ushort* w_lo = ws + WLO_OFF;
    ushort* q_hi = ws + QHI_OFF;
    ushort* q_lo = ws + QLO_OFF;
    ushort* k_hi = ws + KHI_OFF;
    ushort* k_lo = ws + KLO_OFF;
    ushort* v_t  = ws + VT_OFF;

    split_w_kernel<<<dim3(576), dim3(256), 0, stream>>>(Wq, Wk, Wv, w_hi, w_lo);
    proj_kernel<<<dim3(512), dim3(256), 0, stream>>>(x, w_hi, w_lo,
                                                     q_hi, q_lo, k_hi, k_lo, v_t);
    attn_kernel<<<dim3(1024), dim3(256), 0, stream>>>(q_hi, q_lo, k_hi, k_lo, v_t, out);
}

// Round 6
// 70.890 us; speedup vs baseline: 1.2995x; 1.2995x over previous
//
#include <hip/hip_runtime.h>
#include <math.h>

#define EMBED 768
#define SEQ   2048
#define NB    8
// sqrt(768) * log2(e): scores are produced directly in log2 domain
#define QSCALE 39.98113776623437f

typedef short  short8 __attribute__((ext_vector_type(8)));
typedef float  f32x4  __attribute__((ext_vector_type(4)));

// ws layout, ushort element offsets
#define WHI_OFF  0u
#define WLO_OFF  147456u
#define QHI_OFF  294912u
#define QLO_OFF  (294912u + 1u*1048576u)
#define KHI_OFF  (294912u + 2u*1048576u)
#define KLO_OFF  (294912u + 3u*1048576u)
#define VT_OFF   (294912u + 4u*1048576u)
// float element offsets (from (float*)d_ws); ushort region = 5,537,792 elems
#define FLT_BASE 2768896u
#define OP_OFF   FLT_BASE                  // float oP[2][NB*SEQ*64]
#define MP_OFF   (FLT_BASE + 2097152u)     // float mP[2][NB*SEQ]
#define LP_OFF   (MP_OFF + 32768u)         // float lP[2][NB*SEQ]

__device__ __forceinline__ ushort f2bf(float f) {          // round-to-nearest
    unsigned u = __float_as_uint(f);
    return (ushort)((u + 0x7FFFu + ((u >> 16) & 1u)) >> 16);
}
__device__ __forceinline__ ushort f2bf_trunc(float f) {    // cheap, for lo part
    return (ushort)(__float_as_uint(f) >> 16);
}
__device__ __forceinline__ float bf2f(ushort h) {
    return __uint_as_float(((unsigned)h) << 16);
}

// ---------------------------------------------------------------------------
// Kernel 0: split W into bf16 hi/lo.  rows: [0,64)=Wq*QSCALE, [64,128)=Wk,
// [128,192)=Wv.  (q scale carries sqrt(768)*log2e so scores are log2-domain.)
// ---------------------------------------------------------------------------
__global__ __launch_bounds__(256)
void split_w_kernel(const float* __restrict__ Wq, const float* __restrict__ Wk,
                    const float* __restrict__ Wv,
                    ushort* __restrict__ w_hi, ushort* __restrict__ w_lo)
{
    int idx = blockIdx.x * 256 + threadIdx.x;
    if (idx >= 192 * EMBED) return;
    int row = idx / EMBED, e = idx - row * EMBED;
    float f;
    if (row < 64)       f = Wq[row * EMBED + e] * QSCALE;
    else if (row < 128) f = Wk[(row - 64) * EMBED + e];
    else                f = Wv[(row - 128) * EMBED + e];
    ushort hi = f2bf(f);
    w_hi[idx] = hi;
    w_lo[idx] = f2bf_trunc(f - bf2f(hi));
}

// ---------------------------------------------------------------------------
// Kernel 1: QKV projection (unchanged from R5: LDS-staged, register prefetch,
// BM=32, 2 blocks/CU).  q/k cols 3-product split-bf16; v single product.
// ---------------------------------------------------------------------------
__global__ __launch_bounds__(256)
void proj_kernel(const float* __restrict__ x,
                 const ushort* __restrict__ w_hi, const ushort* __restrict__ w_lo,
                 ushort* __restrict__ q_hi, ushort* __restrict__ q_lo,
                 ushort* __restrict__ k_hi, ushort* __restrict__ k_lo,
                 ushort* __restrict__ v_t)
{
    __shared__ __align__(16) ushort xa_hi[32][72], xa_lo[32][72];
    __shared__ __align__(16) ushort wb_hi[192][72];
    __shared__ __align__(16) ushort wb_lo[128][72];

    const int t    = threadIdx.x;
    const int lane = t & 63;
    const int wid  = t >> 6;
    const int wm   = wid >> 1;
    const int ch   = wid & 1;
    const int ln   = lane & 15;
    const int kg   = lane >> 4;
    const int row0 = blockIdx.x * 32;

    const int srow = t >> 3;
    const int scol = (t & 7) * 8;
    const int wrow = t >> 2;
    const int wcol = (t & 3) * 16;

    float4 xr0, xr1;
    short8 wh0, wh1, wh2, wh3, wh4, wh5;
    short8 wl0, wl1, wl2, wl3;

#define LOAD_CHUNK(e0) do {                                                     \
        const float*  xp_ = x + (size_t)(row0 + srow) * EMBED + (e0) + scol;    \
        xr0 = *(const float4*)xp_;  xr1 = *(const float4*)(xp_ + 4);            \
        const ushort* whp_ = w_hi + (size_t)wrow * EMBED + (e0) + wcol;         \
        wh0 = *(const short8*)whp_;                                             \
        wh1 = *(const short8*)(whp_ + 8);                                       \
        wh2 = *(const short8*)(whp_ + 64 * EMBED);                              \
        wh3 = *(const short8*)(whp_ + 64 * EMBED + 8);                          \
        wh4 = *(const short8*)(whp_ + 128 * EMBED);                             \
        wh5 = *(const short8*)(whp_ + 128 * EMBED + 8);                         \
        const ushort* wlp_ = w_lo + (size_t)wrow * EMBED + (e0) + wcol;         \
        wl0 = *(const short8*)wlp_;                                             \
        wl1 = *(const short8*)(wlp_ + 8);                                       \
        wl2 = *(const short8*)(wlp_ + 64 * EMBED);                              \
        wl3 = *(const short8*)(wlp_ + 64 * EMBED + 8);                          \
    } while (0)

    const f32x4 vzero = {0.f, 0.f, 0.f, 0.f};
    f32x4 acc[6];
#pragma unroll
    for (int j = 0; j < 6; ++j) acc[j] = vzero;

    LOAD_CHUNK(0);

    for (int c = 0; c < 12; ++c) {
        if (c) __syncthreads();
        {
            const float fv[8] = {xr0.x, xr0.y, xr0.z, xr0.w,
                                 xr1.x, xr1.y, xr1.z, xr1.w};
            short8 h0, l0;
#pragma unroll
            for (int i = 0; i < 8; ++i) {
                ushort h = f2bf(fv[i]);
                h0[i] = (short)h;
                l0[i] = (short)f2bf_trunc(fv[i] - bf2f(h));
            }
            *(short8*)&xa_hi[srow][scol] = h0;
            *(short8*)&xa_lo[srow][scol] = l0;
            *(short8*)&wb_hi[wrow][wcol]           = wh0;
            *(short8*)&wb_hi[wrow][wcol + 8]       = wh1;
            *(short8*)&wb_hi[wrow + 64][wcol]      = wh2;
            *(short8*)&wb_hi[wrow + 64][wcol + 8]  = wh3;
            *(short8*)&wb_hi[wrow + 128][wcol]     = wh4;
            *(short8*)&wb_hi[wrow + 128][wcol + 8] = wh5;
            *(short8*)&wb_lo[wrow][wcol]           = wl0;
            *(short8*)&wb_lo[wrow][wcol + 8]       = wl1;
            *(short8*)&wb_lo[wrow + 64][wcol]      = wl2;
            *(short8*)&wb_lo[wrow + 64][wcol + 8]  = wl3;
        }
        __syncthreads();
        if (c < 11) LOAD_CHUNK((c + 1) * 64);

        short8 ah[2], al[2];
#pragma unroll
        for (int ks = 0; ks < 2; ++ks) {
            ah[ks] = *(const short8*)&xa_hi[wm * 16 + ln][ks * 32 + kg * 8];
            al[ks] = *(const short8*)&xa_lo[wm * 16 + ln][ks * 32 + kg * 8];
        }
#pragma unroll
        for (int j = 0; j < 6; ++j) {
            const int ntg = 2 * j + ch;
#pragma unroll
            for (int ks = 0; ks < 2; ++ks) {
                short8 bh = *(const short8*)&wb_hi[ntg * 16 + ln][ks * 32 + kg * 8];
                acc[j] = __builtin_amdgcn_mfma_f32_16x16x32_bf16(ah[ks], bh, acc[j], 0, 0, 0);
                if (j < 4) {
                    short8 bl = *(const short8*)&wb_lo[ntg * 16 + ln][ks * 32 + kg * 8];
                    acc[j] = __builtin_amdgcn_mfma_f32_16x16x32_bf16(ah[ks], bl, acc[j], 0, 0, 0);
                    acc[j] = __builtin_amdgcn_mfma_f32_16x16x32_bf16(al[ks], bh, acc[j], 0, 0, 0);
                }
            }
        }
    }
#undef LOAD_CHUNK

    {
        const int rbase = row0 + wm * 16 + kg * 4;
#pragma unroll
        for (int j = 0; j < 6; ++j) {
            const int ntg = 2 * j + ch;
            const int col = ntg * 16 + ln;
#pragma unroll
            for (int r = 0; r < 4; ++r) {
                int rg = rbase + r;
                int b = rg >> 11, s = rg & 2047;
                size_t rowoff = ((size_t)b * SEQ + s) * 64;
                float val = acc[j][r];
                if (col < 64) {
                    ushort h = f2bf(val);
                    q_hi[rowoff + col] = h;
                    q_lo[rowoff + col] = f2bf_trunc(val - bf2f(h));
                } else if (col < 128) {
                    ushort h = f2bf(val);
                    k_hi[rowoff + (col - 64)] = h;
                    k_lo[rowoff + (col - 64)] = f2bf_trunc(val - bf2f(h));
                } else {
                    v_t[((size_t)b * 64 + (col - 128)) * SEQ + s] = f2bf(val);
                }
            }
        }
    }
}

// ---------------------------------------------------------------------------
// Kernel 2: causal flash attention, 64-row q-blocks, LDS double-buffered K/V
// via global_load_lds (shared by 4 waves), 2-phase counted-prefetch schedule.
// Block = pair (qA=31-p, qB=p) x k-parity z -> 16..17 passes for EVERY block.
// Partials (o, m, l) to workspace; merge_kernel combines the 2 parities.
// LDS tiles are linear [64][64]; bank-conflict-free via inverse-swizzled
// global SOURCE + XOR-swizzled ds_read (elem ^= (row&7)<<3)  [rule 21].
// Swapped QK^T (lane ln owns query-column), log2-domain softmax (exp2f).
// ---------------------------------------------------------------------------
__global__ __launch_bounds__(256)
void attn_kernel(const ushort* __restrict__ q_hi, const ushort* __restrict__ q_lo,
                 const ushort* __restrict__ k_hi, const ushort* __restrict__ k_lo,
                 const ushort* __restrict__ v_t,
                 float* __restrict__ oP, float* __restrict__ mP, float* __restrict__ lP)
{
    __shared__ __align__(16) ushort kv[2][3][64][64];   // [buf][Khi|Klo|V][row][col]
    __shared__ __align__(16) ushort pT[4][16][72];

    const int t    = threadIdx.x;
    const int lane = t & 63;
    const int w    = t >> 6;          // wave 0..3 -> rows w*16..+15 of the q-block
    const int ln   = lane & 15;
    const int kg   = lane >> 4;       // 0..3
    const int b    = blockIdx.x & 7;          // batch -> XCD
    const int pr   = (blockIdx.x >> 3) & 15;  // pair id
    const int z    = (blockIdx.x >> 7) & 1;   // k-parity
    const int qA   = 31 - pr;                 // big 64-row q-block
    const int qB2  = pr;                      // small 64-row q-block
    const int c1   = (qA - z) / 2 + 1;
    const int c2   = (qB2 >= z) ? (qB2 - z) / 2 + 1 : 0;
    const int tot  = c1 + c2;

    const ushort* qhb = q_hi + (size_t)b * SEQ * 64;
    const ushort* qlb = q_lo + (size_t)b * SEQ * 64;
    const ushort* khb = k_hi + (size_t)b * SEQ * 64;
    const ushort* klb = k_lo + (size_t)b * SEQ * 64;
    const ushort* vtb = v_t + (size_t)b * 64 * SEQ;

    // Q fragments for both q-blocks (hi/lo, 2 k-steps each)
    short8 qhA[2], qlA[2], qhB[2], qlB[2];
#pragma unroll
    for (int ks = 0; ks < 2; ++ks) {
        size_t offA = (size_t)(qA * 64 + w * 16 + ln) * 64 + ks * 32 + kg * 8;
        size_t offB = (size_t)(qB2 * 64 + w * 16 + ln) * 64 + ks * 32 + kg * 8;
        qhA[ks] = *(const short8*)(qhb + offA);
        qlA[ks] = *(const short8*)(qlb + offA);
        qhB[ks] = *(const short8*)(qhb + offB);
        qlB[ks] = *(const short8*)(qlb + offB);
    }

    const f32x4 vzero = {0.f, 0.f, 0.f, 0.f};
    f32x4 oA[4], oB[4];
    float mA = -INFINITY, lA = 0.f, mB = -INFINITY, lB = 0.f;
#pragma unroll
    for (int i = 0; i < 4; ++i) { oA[i] = vzero; oB[i] = vzero; }

    // ---- staging: 24 x 1KB DMA insts per tile, 6 per wave ----
    const int si    = w * 6;
    const int srow8 = lane >> 3;                               // 0..7
    const int scol  = ((lane & 7) << 3) ^ ((lane >> 3) << 3);  // inverse swizzle

    auto stage = [&](int pass, int cbuf) {
        const int kk = (pass < c1) ? (z + 2 * pass) : (z + 2 * (pass - c1));
        const int j0 = kk << 6;
        ushort* base = &kv[cbuf][0][0][0];
#pragma unroll
        for (int s = 0; s < 6; ++s) {
            const int i = si + s;
            const int row = ((i & 7) << 3) + srow8;
            const ushort* g;
            if (i < 8)       g = khb + (size_t)(j0 + row) * 64 + scol;
            else if (i < 16) g = klb + (size_t)(j0 + row) * 64 + scol;
            else             g = vtb + (size_t)row * SEQ + j0 + scol;
            __builtin_amdgcn_global_load_lds(
                (const __attribute__((address_space(1))) void*)g,
                (__attribute__((address_space(3))) void*)(base + i * 512),
                16, 0, 0);
        }
    };

    // ---- per-pass compute ----
    auto body = [&](int kk, int qblk, f32x4 (&o)[4], float& m_run, float& l_run,
                    short8 (&qh)[2], short8 (&ql)[2], int cbuf) {
        const ushort* K0 = &kv[cbuf][0][0][0];
        const ushort* K1 = &kv[cbuf][1][0][0];
        const ushort* VT = &kv[cbuf][2][0][0];
        const int xorc = (ln & 7) << 3;

        f32x4 sacc[4];
#pragma unroll
        for (int ct = 0; ct < 4; ++ct) sacc[ct] = vzero;
#pragma unroll
        for (int ct = 0; ct < 4; ++ct) {
            const int rb = (ct * 16 + ln) * 64;
#pragma unroll
            for (int ks = 0; ks < 2; ++ks) {
                const int co = (ks * 32 + kg * 8) ^ xorc;
                short8 bh = *(const short8*)(K0 + rb + co);
                short8 bl = *(const short8*)(K1 + rb + co);
                sacc[ct] = __builtin_amdgcn_mfma_f32_16x16x32_bf16(bh, qh[ks], sacc[ct], 0, 0, 0);
                sacc[ct] = __builtin_amdgcn_mfma_f32_16x16x32_bf16(bh, ql[ks], sacc[ct], 0, 0, 0);
                sacc[ct] = __builtin_amdgcn_mfma_f32_16x16x32_bf16(bl, qh[ks], sacc[ct], 0, 0, 0);
            }
        }

        // causal mask (only the diagonal tile of this q-block)
        if (kk == qblk) {
            const int qrow = qblk * 64 + w * 16 + ln;
#pragma unroll
            for (int ct = 0; ct < 4; ++ct) {
                int kb0 = kk * 64 + ct * 16 + kg * 4;
#pragma unroll
                for (int r = 0; r < 4; ++r)
                    if (kb0 + r > qrow) sacc[ct][r] = -1e30f;
            }
        }

        // online softmax (log2 domain) for query ln: 16 local + 2 shfl
        float mt_ = fmaxf(fmaxf(fmaxf(sacc[0][0], sacc[0][1]), fmaxf(sacc[0][2], sacc[0][3])),
                          fmaxf(fmaxf(sacc[1][0], sacc[1][1]), fmaxf(sacc[1][2], sacc[1][3])));
        float mt2 = fmaxf(fmaxf(fmaxf(sacc[2][0], sacc[2][1]), fmaxf(sacc[2][2], sacc[2][3])),
                          fmaxf(fmaxf(sacc[3][0], sacc[3][1]), fmaxf(sacc[3][2], sacc[3][3])));
        mt_ = fmaxf(mt_, mt2);
        mt_ = fmaxf(mt_, __shfl_xor(mt_, 16));
        mt_ = fmaxf(mt_, __shfl_xor(mt_, 32));
        float mn   = fmaxf(m_run, mt_);
        float corr = exp2f(m_run - mn);      // 0 on first tile
        float p[4][4];
        float lt = 0.f;
#pragma unroll
        for (int ct = 0; ct < 4; ++ct)
#pragma unroll
            for (int r = 0; r < 4; ++r) {
                p[ct][r] = exp2f(sacc[ct][r] - mn);
                lt += p[ct][r];
            }
        lt += __shfl_xor(lt, 16);
        lt += __shfl_xor(lt, 32);
        m_run = mn;
        l_run = l_run * corr + lt;

        // P -> per-wave LDS (bf16 packed)
#pragma unroll
        for (int ct = 0; ct < 4; ++ct) {
            uint u0 = (uint)f2bf(p[ct][0]) | ((uint)f2bf(p[ct][1]) << 16);
            uint u1 = (uint)f2bf(p[ct][2]) | ((uint)f2bf(p[ct][3]) << 16);
            *(uint*)&pT[w][ln][ct * 16 + kg * 4]     = u0;
            *(uint*)&pT[w][ln][ct * 16 + kg * 4 + 2] = u1;
        }
        // rescale O (rows q = kg*4+r)
        float corrq[4];
#pragma unroll
        for (int r = 0; r < 4; ++r) corrq[r] = __shfl(corr, kg * 4 + r);
#pragma unroll
        for (int ht = 0; ht < 4; ++ht)
#pragma unroll
            for (int r = 0; r < 4; ++r) o[ht][r] *= corrq[r];
        // PV
#pragma unroll
        for (int ks = 0; ks < 2; ++ks) {
            short8 pa = *(const short8*)&pT[w][ln][ks * 32 + kg * 8];
#pragma unroll
            for (int ht = 0; ht < 4; ++ht) {
                const int co = (ks * 32 + kg * 8) ^ xorc;
                short8 bv = *(const short8*)(VT + (ht * 16 + ln) * 64 + co);
                o[ht] = __builtin_amdgcn_mfma_f32_16x16x32_bf16(pa, bv, o[ht], 0, 0, 0);
            }
        }
    };

    // ---- 2-phase pipelined pass loop ----
    stage(0, 0);
    __syncthreads();
    int cur = 0;
    for (int pass = 0; pass < tot; ++pass) {
        if (pass + 1 < tot) stage(pass + 1, cur ^ 1);
        const int kk = (pass < c1) ? (z + 2 * pass) : (z + 2 * (pass - c1));
        if (pass < c1) body(kk, qA,  oA, mA, lA, qhA, qlA, cur);
        else           body(kk, qB2, oB, mB, lB, qhB, qlB, cur);
        __syncthreads();
        cur ^= 1;
    }

    // ---- store partials ----
    float* oPz = oP + (size_t)z * 1048576u;
    float* mPz = mP + (size_t)z * 16384u;
    float* lPz = lP + (size_t)z * 16384u;
    {
        const size_t rowg = (size_t)b * SEQ + qA * 64 + w * 16;
#pragma unroll
        for (int ht = 0; ht < 4; ++ht)
#pragma unroll
            for (int r = 0; r < 4; ++r)
                oPz[(rowg + kg * 4 + r) * 64 + ht * 16 + ln] = oA[ht][r];
        if (kg == 0) { mPz[rowg + ln] = mA; lPz[rowg + ln] = lA; }
    }
    {
        const size_t rowg = (size_t)b * SEQ + qB2 * 64 + w * 16;
#pragma unroll
        for (int ht = 0; ht < 4; ++ht)
#pragma unroll
            for (int r = 0; r < 4; ++r)
                oPz[(rowg + kg * 4 + r) * 64 + ht * 16 + ln] = oB[ht][r];
        if (kg == 0) { mPz[rowg + ln] = mB; lPz[rowg + ln] = lB; }
    }
}

// ---------------------------------------------------------------------------
// Kernel 3: merge the two k-parity partials.  out = (o0*c0+o1*c1)/(l0*c0+l1*c1)
// with cz = exp2(mz - max(m0,m1)).  1,048,576 out elems, float4 per thread.
// ---------------------------------------------------------------------------
__global__ __launch_bounds__(256)
void merge_kernel(const float* __restrict__ oP, const float* __restrict__ mP,
                  const float* __restrict__ lP, float* __restrict__ out)
{
    int idx = blockIdx.x * 256 + threadIdx.x;   // 0..262143
    int R  = idx >> 4;
    int h0 = (idx & 15) << 2;
    float m0 = mP[R], m1 = mP[16384 + R];
    float l0 = lP[R], l1 = lP[16384 + R];
    float M  = fmaxf(m0, m1);
    float c0 = exp2f(m0 - M), c1 = exp2f(m1 - M);
    float inv = 1.0f / (l0 * c0 + l1 * c1);
    float4 a = *(const float4*)(oP + (size_t)R * 64 + h0);
    float4 d = *(const float4*)(oP + 1048576u + (size_t)R * 64 + h0);
    float4 r;
    r.x = (a.x * c0 + d.x * c1) * inv;
    r.y = (a.y * c0 + d.y * c1) * inv;
    r.z = (a.z * c0 + d.z * c1) * inv;
    r.w = (a.w * c0 + d.w * c1) * inv;
    *(float4*)(out + (size_t)R * 64 + h0) = r;
}

// ---------------------------------------------------------------------------
extern "C" void kernel_launch(void* const* d_in, const int* in_sizes, int n_in,
                              void* d_out, int out_size, void* d_ws, size_t ws_size,
                              hipStream_t stream)
{
    const float* x  = (const float*)d_in[0];
    const float* Wq = (const float*)d_in[1];
    const float* Wk = (const float*)d_in[2];
    const float* Wv = (const float*)d_in[3];
    float* out = (float*)d_out;

    ushort* ws = (ushort*)d_ws;
    float*  wsf = (float*)d_ws;
    ushort* w_hi = ws + WHI_OFF;
    ushort* w_lo = ws + WLO_OFF;
    ushort* q_hi = ws + QHI_OFF;
    ushort* q_lo = ws + QLO_OFF;
    ushort* k_hi = ws + KHI_OFF;
    ushort* k_lo = ws + KLO_OFF;
    ushort* v_t  = ws + VT_OFF;
    float*  oP   = wsf + OP_OFF;
    float*  mP   = wsf + MP_OFF;
    float*  lP   = wsf + LP_OFF;

    split_w_kernel<<<dim3(576), dim3(256), 0, stream>>>(Wq, Wk, Wv, w_hi, w_lo);
    proj_kernel<<<dim3(512), dim3(256), 0, stream>>>(x, w_hi, w_lo,
                                                     q_hi, q_lo, k_hi, k_lo, v_t);
    attn_kernel<<<dim3(256), dim3(256), 0, stream>>>(q_hi, q_lo, k_hi, k_lo, v_t,
                                                     oP, mP, lP);
    merge_kernel<<<dim3(1024), dim3(256), 0, stream>>>(oP, mP, lP, out);
}

// Round 7
// 60.844 us; speedup vs baseline: 1.5141x; 1.1651x over previous
//
#include <hip/hip_runtime.h>
#include <math.h>

#define EMBED 768
#define SEQ   2048
#define NB    8
// sqrt(768) * log2(e): scores are produced directly in log2 domain
#define QSCALE 39.98113776623437f

typedef short  short8 __attribute__((ext_vector_type(8)));
typedef float  f32x4  __attribute__((ext_vector_type(4)));

// ws layout, ushort element offsets
#define WHI_OFF  0u
#define WLO_OFF  147456u
#define QHI_OFF  294912u
#define QLO_OFF  (294912u + 1u*1048576u)
#define KHI_OFF  (294912u + 2u*1048576u)
#define KLO_OFF  (294912u + 3u*1048576u)
#define VT_OFF   (294912u + 4u*1048576u)
// float element offsets (from (float*)d_ws); ushort region = 5,537,792 elems
#define FLT_BASE 2768896u
#define OP_OFF   FLT_BASE                  // float oP[4][NB*SEQ*64]
#define MP_OFF   (FLT_BASE + 4194304u)     // float mP[4][NB*SEQ]
#define LP_OFF   (MP_OFF + 65536u)         // float lP[4][NB*SEQ]

__device__ __forceinline__ ushort f2bf(float f) {          // round-to-nearest
    unsigned u = __float_as_uint(f);
    return (ushort)((u + 0x7FFFu + ((u >> 16) & 1u)) >> 16);
}
__device__ __forceinline__ ushort f2bf_trunc(float f) {    // cheap, for lo part
    return (ushort)(__float_as_uint(f) >> 16);
}
__device__ __forceinline__ float bf2f(ushort h) {
    return __uint_as_float(((unsigned)h) << 16);
}

// ---------------------------------------------------------------------------
// Kernel 0: split W into bf16 hi/lo.  rows: [0,64)=Wq*QSCALE, [64,128)=Wk,
// [128,192)=Wv.
// ---------------------------------------------------------------------------
__global__ __launch_bounds__(256)
void split_w_kernel(const float* __restrict__ Wq, const float* __restrict__ Wk,
                    const float* __restrict__ Wv,
                    ushort* __restrict__ w_hi, ushort* __restrict__ w_lo)
{
    int idx = blockIdx.x * 256 + threadIdx.x;
    if (idx >= 192 * EMBED) return;
    int row = idx / EMBED, e = idx - row * EMBED;
    float f;
    if (row < 64)       f = Wq[row * EMBED + e] * QSCALE;
    else if (row < 128) f = Wk[(row - 64) * EMBED + e];
    else                f = Wv[(row - 128) * EMBED + e];
    ushort hi = f2bf(f);
    w_hi[idx] = hi;
    w_lo[idx] = f2bf_trunc(f - bf2f(hi));
}

// ---------------------------------------------------------------------------
// Kernel 1: QKV projection.  BM=32, grid 512, 2 blocks/CU resident.
// Block = 256 thr = 4 waves; wave wid covers ALL 32 rows (2 m-tiles) x
// 3 n-tiles {wid, 4+wid, 8+wid} = exactly 1 q-tile + 1 k-tile + 1 v-tile
// -> 28 MFMA per chunk against 18 ds_read_b128 (vs 28 reads in R5).
// K-chunk 64 (12 chunks), W register-prefetch across the barriers.
// ---------------------------------------------------------------------------
__global__ __launch_bounds__(256)
void proj_kernel(const float* __restrict__ x,
                 const ushort* __restrict__ w_hi, const ushort* __restrict__ w_lo,
                 ushort* __restrict__ q_hi, ushort* __restrict__ q_lo,
                 ushort* __restrict__ k_hi, ushort* __restrict__ k_lo,
                 ushort* __restrict__ v_t)
{
    __shared__ __align__(16) ushort xa_hi[32][72], xa_lo[32][72];
    __shared__ __align__(16) ushort wbh[192][72];
    __shared__ __align__(16) ushort wbl[128][72];

    const int t    = threadIdx.x;
    const int lane = t & 63;
    const int wid  = t >> 6;        // wave id 0..3 -> n-tiles {wid, 4+wid, 8+wid}
    const int ln   = lane & 15;
    const int kg   = lane >> 4;     // 0..3
    const int row0 = blockIdx.x * 32;

    const int srow = t >> 3;            // 0..31 (x staging row)
    const int scol = (t & 7) * 8;       // x staging col (8 floats)
    const int wrow = t >> 2;            // 0..63 (W staging row)
    const int wcol = (t & 3) * 16;      // W staging col (16 elems)

    float4 xr0, xr1;
    short8 wh0, wh1, wh2, wh3, wh4, wh5;
    short8 wl0, wl1, wl2, wl3;

#define LOAD_CHUNK(e0) do {                                                     \
        const float*  xp_ = x + (size_t)(row0 + srow) * EMBED + (e0) + scol;    \
        xr0 = *(const float4*)xp_;  xr1 = *(const float4*)(xp_ + 4);            \
        const ushort* whp_ = w_hi + (size_t)wrow * EMBED + (e0) + wcol;         \
        wh0 = *(const short8*)whp_;                                             \
        wh1 = *(const short8*)(whp_ + 8);                                       \
        wh2 = *(const short8*)(whp_ + 64 * EMBED);                              \
        wh3 = *(const short8*)(whp_ + 64 * EMBED + 8);                          \
        wh4 = *(const short8*)(whp_ + 128 * EMBED);                             \
        wh5 = *(const short8*)(whp_ + 128 * EMBED + 8);                         \
        const ushort* wlp_ = w_lo + (size_t)wrow * EMBED + (e0) + wcol;         \
        wl0 = *(const short8*)wlp_;                                             \
        wl1 = *(const short8*)(wlp_ + 8);                                       \
        wl2 = *(const short8*)(wlp_ + 64 * EMBED);                              \
        wl3 = *(const short8*)(wlp_ + 64 * EMBED + 8);                          \
    } while (0)

    const f32x4 vzero = {0.f, 0.f, 0.f, 0.f};
    f32x4 acc[2][3];                 // [m-tile][q|k|v tile]
#pragma unroll
    for (int mt = 0; mt < 2; ++mt)
#pragma unroll
        for (int j = 0; j < 3; ++j) acc[mt][j] = vzero;

    LOAD_CHUNK(0);

    for (int c = 0; c < 12; ++c) {
        if (c) __syncthreads();
        {
            const float fv[8] = {xr0.x, xr0.y, xr0.z, xr0.w,
                                 xr1.x, xr1.y, xr1.z, xr1.w};
            short8 h0, l0;
#pragma unroll
            for (int i = 0; i < 8; ++i) {
                ushort h = f2bf(fv[i]);
                h0[i] = (short)h;
                l0[i] = (short)f2bf_trunc(fv[i] - bf2f(h));
            }
            *(short8*)&xa_hi[srow][scol] = h0;
            *(short8*)&xa_lo[srow][scol] = l0;
            *(short8*)&wbh[wrow][wcol]           = wh0;
            *(short8*)&wbh[wrow][wcol + 8]       = wh1;
            *(short8*)&wbh[wrow + 64][wcol]      = wh2;
            *(short8*)&wbh[wrow + 64][wcol + 8]  = wh3;
            *(short8*)&wbh[wrow + 128][wcol]     = wh4;
            *(short8*)&wbh[wrow + 128][wcol + 8] = wh5;
            *(short8*)&wbl[wrow][wcol]           = wl0;
            *(short8*)&wbl[wrow][wcol + 8]       = wl1;
            *(short8*)&wbl[wrow + 64][wcol]      = wl2;
            *(short8*)&wbl[wrow + 64][wcol + 8]  = wl3;
        }
        __syncthreads();
        if (c < 11) LOAD_CHUNK((c + 1) * 64);

        // fragments: all 32 rows (2 m-tiles), hi/lo, 2 k-steps  -> 8 reads
        short8 ah[2][2], al[2][2];
#pragma unroll
        for (int mt = 0; mt < 2; ++mt)
#pragma unroll
            for (int ks = 0; ks < 2; ++ks) {
                ah[mt][ks] = *(const short8*)&xa_hi[mt * 16 + ln][ks * 32 + kg * 8];
                al[mt][ks] = *(const short8*)&xa_lo[mt * 16 + ln][ks * 32 + kg * 8];
            }
        // q-tile (ntg=wid) and k-tile (ntg=4+wid): 3-product split; v: single
#pragma unroll
        for (int j = 0; j < 3; ++j) {
            const int ntg = j * 4 + wid;
#pragma unroll
            for (int ks = 0; ks < 2; ++ks) {
                const int co = ks * 32 + kg * 8;
                if (j < 2) {
                    short8 bh = *(const short8*)&wbh[ntg * 16 + ln][co];
                    short8 bl = *(const short8*)&wbl[ntg * 16 + ln][co];
#pragma unroll
                    for (int mt = 0; mt < 2; ++mt) {
                        acc[mt][j] = __builtin_amdgcn_mfma_f32_16x16x32_bf16(ah[mt][ks], bh, acc[mt][j], 0, 0, 0);
                        acc[mt][j] = __builtin_amdgcn_mfma_f32_16x16x32_bf16(ah[mt][ks], bl, acc[mt][j], 0, 0, 0);
                        acc[mt][j] = __builtin_amdgcn_mfma_f32_16x16x32_bf16(al[mt][ks], bh, acc[mt][j], 0, 0, 0);
                    }
                } else {
                    short8 bh = *(const short8*)&wbh[ntg * 16 + ln][co];
#pragma unroll
                    for (int mt = 0; mt < 2; ++mt)
                        acc[mt][j] = __builtin_amdgcn_mfma_f32_16x16x32_bf16(ah[mt][ks], bh, acc[mt][j], 0, 0, 0);
                }
            }
        }
    }
#undef LOAD_CHUNK

    // epilogue: C layout col=lane&15, row=(lane>>4)*4+reg
#pragma unroll
    for (int mt = 0; mt < 2; ++mt) {
        const int rbase = row0 + mt * 16 + kg * 4;
#pragma unroll
        for (int j = 0; j < 3; ++j) {
            const int col = (j * 4 + wid) * 16 + ln;
#pragma unroll
            for (int r = 0; r < 4; ++r) {
                int rg = rbase + r;
                int b = rg >> 11, s = rg & 2047;
                size_t rowoff = ((size_t)b * SEQ + s) * 64;
                float val = acc[mt][j][r];
                if (col < 64) {
                    ushort h = f2bf(val);
                    q_hi[rowoff + col] = h;
                    q_lo[rowoff + col] = f2bf_trunc(val - bf2f(h));
                } else if (col < 128) {
                    ushort h = f2bf(val);
                    k_hi[rowoff + (col - 64)] = h;
                    k_lo[rowoff + (col - 64)] = f2bf_trunc(val - bf2f(h));
                } else {
                    v_t[((size_t)b * 64 + (col - 128)) * SEQ + s] = f2bf(val);
                }
            }
        }
    }
}

// ---------------------------------------------------------------------------
// Kernel 2: causal flash attention, 64-row q-blocks, LDS double-buffered K/V
// via global_load_lds, k-parity split FOUR ways (z = k-tile index mod 4).
// Grid = 8 b x 16 pr x 4 z = 512 blocks -> 2 blocks/CU resident; balanced
// pass counts (8-9 for every block).  Partials to workspace; merge combines.
// ---------------------------------------------------------------------------
__global__ __launch_bounds__(256)
void attn_kernel(const ushort* __restrict__ q_hi, const ushort* __restrict__ q_lo,
                 const ushort* __restrict__ k_hi, const ushort* __restrict__ k_lo,
                 const ushort* __restrict__ v_t,
                 float* __restrict__ oP, float* __restrict__ mP, float* __restrict__ lP)
{
    __shared__ __align__(16) ushort kv[2][3][64][64];   // [buf][Khi|Klo|V][row][col]
    __shared__ __align__(16) ushort pT[4][16][72];

    const int t    = threadIdx.x;
    const int lane = t & 63;
    const int w    = t >> 6;          // wave 0..3 -> rows w*16..+15 of q-block
    const int ln   = lane & 15;
    const int kg   = lane >> 4;       // 0..3
    const int b    = blockIdx.x & 7;          // batch -> XCD
    const int pr   = (blockIdx.x >> 3) & 15;  // pair id
    const int z    = (blockIdx.x >> 7) & 3;   // k-tile parity (mod 4)
    const int qA   = 31 - pr;                 // big 64-row q-block
    const int qB2  = pr;                      // small 64-row q-block
    const int c1   = (qA - z) / 4 + 1;                       // qA >= 16 > z
    const int c2   = (qB2 >= z) ? (qB2 - z) / 4 + 1 : 0;
    const int tot  = c1 + c2;

    const ushort* qhb = q_hi + (size_t)b * SEQ * 64;
    const ushort* qlb = q_lo + (size_t)b * SEQ * 64;
    const ushort* khb = k_hi + (size_t)b * SEQ * 64;
    const ushort* klb = k_lo + (size_t)b * SEQ * 64;
    const ushort* vtb = v_t + (size_t)b * 64 * SEQ;

    // Q fragments for both q-blocks (hi/lo, 2 k-steps each)
    short8 qhA[2], qlA[2], qhB[2], qlB[2];
#pragma unroll
    for (int ks = 0; ks < 2; ++ks) {
        size_t offA = (size_t)(qA * 64 + w * 16 + ln) * 64 + ks * 32 + kg * 8;
        size_t offB = (size_t)(qB2 * 64 + w * 16 + ln) * 64 + ks * 32 + kg * 8;
        qhA[ks] = *(const short8*)(qhb + offA);
        qlA[ks] = *(const short8*)(qlb + offA);
        qhB[ks] = *(const short8*)(qhb + offB);
        qlB[ks] = *(const short8*)(qlb + offB);
    }

    const f32x4 vzero = {0.f, 0.f, 0.f, 0.f};
    f32x4 oA[4], oB[4];
    float mA = -INFINITY, lA = 0.f, mB = -INFINITY, lB = 0.f;
#pragma unroll
    for (int i = 0; i < 4; ++i) { oA[i] = vzero; oB[i] = vzero; }

    // ---- staging: 24 x 1KB DMA insts per tile, 6 per wave ----
    const int si    = w * 6;
    const int srow8 = lane >> 3;                               // 0..7
    const int scol  = ((lane & 7) << 3) ^ ((lane >> 3) << 3);  // inverse swizzle

    auto stage = [&](int pass, int cbuf) {
        const int kk = (pass < c1) ? (z + 4 * pass) : (z + 4 * (pass - c1));
        const int j0 = kk << 6;
        ushort* base = &kv[cbuf][0][0][0];
#pragma unroll
        for (int s = 0; s < 6; ++s) {
            const int i = si + s;
            const int row = ((i & 7) << 3) + srow8;
            const ushort* g;
            if (i < 8)       g = khb + (size_t)(j0 + row) * 64 + scol;
            else if (i < 16) g = klb + (size_t)(j0 + row) * 64 + scol;
            else             g = vtb + (size_t)row * SEQ + j0 + scol;
            __builtin_amdgcn_global_load_lds(
                (const __attribute__((address_space(1))) void*)g,
                (__attribute__((address_space(3))) void*)(base + i * 512),
                16, 0, 0);
        }
    };

    // ---- per-pass compute ----
    auto body = [&](int kk, int qblk, f32x4 (&o)[4], float& m_run, float& l_run,
                    short8 (&qh)[2], short8 (&ql)[2], int cbuf) {
        const ushort* K0 = &kv[cbuf][0][0][0];
        const ushort* K1 = &kv[cbuf][1][0][0];
        const ushort* VT = &kv[cbuf][2][0][0];
        const int xorc = (ln & 7) << 3;

        f32x4 sacc[4];
#pragma unroll
        for (int ct = 0; ct < 4; ++ct) sacc[ct] = vzero;
#pragma unroll
        for (int ct = 0; ct < 4; ++ct) {
            const int rb = (ct * 16 + ln) * 64;
#pragma unroll
            for (int ks = 0; ks < 2; ++ks) {
                const int co = (ks * 32 + kg * 8) ^ xorc;
                short8 bh = *(const short8*)(K0 + rb + co);
                short8 bl = *(const short8*)(K1 + rb + co);
                sacc[ct] = __builtin_amdgcn_mfma_f32_16x16x32_bf16(bh, qh[ks], sacc[ct], 0, 0, 0);
                sacc[ct] = __builtin_amdgcn_mfma_f32_16x16x32_bf16(bh, ql[ks], sacc[ct], 0, 0, 0);
                sacc[ct] = __builtin_amdgcn_mfma_f32_16x16x32_bf16(bl, qh[ks], sacc[ct], 0, 0, 0);
            }
        }

        if (kk == qblk) {   // causal mask, diagonal tile only
            const int qrow = qblk * 64 + w * 16 + ln;
#pragma unroll
            for (int ct = 0; ct < 4; ++ct) {
                int kb0 = kk * 64 + ct * 16 + kg * 4;
#pragma unroll
                for (int r = 0; r < 4; ++r)
                    if (kb0 + r > qrow) sacc[ct][r] = -1e30f;
            }
        }

        // online softmax (log2 domain) for query ln: 16 local + 2 shfl
        float mt_ = fmaxf(fmaxf(fmaxf(sacc[0][0], sacc[0][1]), fmaxf(sacc[0][2], sacc[0][3])),
                          fmaxf(fmaxf(sacc[1][0], sacc[1][1]), fmaxf(sacc[1][2], sacc[1][3])));
        float mt2 = fmaxf(fmaxf(fmaxf(sacc[2][0], sacc[2][1]), fmaxf(sacc[2][2], sacc[2][3])),
                          fmaxf(fmaxf(sacc[3][0], sacc[3][1]), fmaxf(sacc[3][2], sacc[3][3])));
        mt_ = fmaxf(mt_, mt2);
        mt_ = fmaxf(mt_, __shfl_xor(mt_, 16));
        mt_ = fmaxf(mt_, __shfl_xor(mt_, 32));
        float mn   = fmaxf(m_run, mt_);
        float corr = exp2f(m_run - mn);      // 0 on first tile
        float p[4][4];
        float lt = 0.f;
#pragma unroll
        for (int ct = 0; ct < 4; ++ct)
#pragma unroll
            for (int r = 0; r < 4; ++r) {
                p[ct][r] = exp2f(sacc[ct][r] - mn);
                lt += p[ct][r];
            }
        lt += __shfl_xor(lt, 16);
        lt += __shfl_xor(lt, 32);
        m_run = mn;
        l_run = l_run * corr + lt;

        // P -> per-wave LDS (bf16 packed)
#pragma unroll
        for (int ct = 0; ct < 4; ++ct) {
            uint u0 = (uint)f2bf(p[ct][0]) | ((uint)f2bf(p[ct][1]) << 16);
            uint u1 = (uint)f2bf(p[ct][2]) | ((uint)f2bf(p[ct][3]) << 16);
            *(uint*)&pT[w][ln][ct * 16 + kg * 4]     = u0;
            *(uint*)&pT[w][ln][ct * 16 + kg * 4 + 2] = u1;
        }
        // rescale O
        float corrq[4];
#pragma unroll
        for (int r = 0; r < 4; ++r) corrq[r] = __shfl(corr, kg * 4 + r);
#pragma unroll
        for (int ht = 0; ht < 4; ++ht)
#pragma unroll
            for (int r = 0; r < 4; ++r) o[ht][r] *= corrq[r];
        // PV
#pragma unroll
        for (int ks = 0; ks < 2; ++ks) {
            short8 pa = *(const short8*)&pT[w][ln][ks * 32 + kg * 8];
#pragma unroll
            for (int ht = 0; ht < 4; ++ht) {
                const int co = (ks * 32 + kg * 8) ^ xorc;
                short8 bv = *(const short8*)(VT + (ht * 16 + ln) * 64 + co);
                o[ht] = __builtin_amdgcn_mfma_f32_16x16x32_bf16(pa, bv, o[ht], 0, 0, 0);
            }
        }
    };

    // ---- 2-phase pipelined pass loop ----
    stage(0, 0);
    __syncthreads();
    int cur = 0;
    for (int pass = 0; pass < tot; ++pass) {
        if (pass + 1 < tot) stage(pass + 1, cur ^ 1);
        const int kk = (pass < c1) ? (z + 4 * pass) : (z + 4 * (pass - c1));
        if (pass < c1) body(kk, qA,  oA, mA, lA, qhA, qlA, cur);
        else           body(kk, qB2, oB, mB, lB, qhB, qlB, cur);
        __syncthreads();
        cur ^= 1;
    }

    // ---- store partials ----
    float* oPz = oP + (size_t)z * 1048576u;
    float* mPz = mP + (size_t)z * 16384u;
    float* lPz = lP + (size_t)z * 16384u;
    {
        const size_t rowg = (size_t)b * SEQ + qA * 64 + w * 16;
#pragma unroll
        for (int ht = 0; ht < 4; ++ht)
#pragma unroll
            for (int r = 0; r < 4; ++r)
                oPz[(rowg + kg * 4 + r) * 64 + ht * 16 + ln] = oA[ht][r];
        if (kg == 0) { mPz[rowg + ln] = mA; lPz[rowg + ln] = lA; }
    }
    {
        const size_t rowg = (size_t)b * SEQ + qB2 * 64 + w * 16;
#pragma unroll
        for (int ht = 0; ht < 4; ++ht)
#pragma unroll
            for (int r = 0; r < 4; ++r)
                oPz[(rowg + kg * 4 + r) * 64 + ht * 16 + ln] = oB[ht][r];
        if (kg == 0) { mPz[rowg + ln] = mB; lPz[rowg + ln] = lB; }
    }
}

// ---------------------------------------------------------------------------
// Kernel 3: merge four k-parity partials.
// ---------------------------------------------------------------------------
__global__ __launch_bounds__(256)
void merge_kernel(const float* __restrict__ oP, const float* __restrict__ mP,
                  const float* __restrict__ lP, float* __restrict__ out)
{
    int idx = blockIdx.x * 256 + threadIdx.x;   // 0..262143
    int R  = idx >> 4;
    int h0 = (idx & 15) << 2;
    float m0 = mP[R],          m1 = mP[16384 + R];
    float m2 = mP[2*16384 + R], m3 = mP[3*16384 + R];
    float l0 = lP[R],          l1 = lP[16384 + R];
    float l2 = lP[2*16384 + R], l3 = lP[3*16384 + R];
    float M  = fmaxf(fmaxf(m0, m1), fmaxf(m2, m3));
    float c0 = exp2f(m0 - M), c1 = exp2f(m1 - M);
    float c2 = exp2f(m2 - M), c3 = exp2f(m3 - M);
    float inv = 1.0f / (l0 * c0 + l1 * c1 + l2 * c2 + l3 * c3);
    float4 a = *(const float4*)(oP + (size_t)R * 64 + h0);
    float4 d = *(const float4*)(oP + 1048576u + (size_t)R * 64 + h0);
    float4 e = *(const float4*)(oP + 2097152u + (size_t)R * 64 + h0);
    float4 f = *(const float4*)(oP + 3145728u + (size_t)R * 64 + h0);
    float4 r;
    r.x = (a.x * c0 + d.x * c1 + e.x * c2 + f.x * c3) * inv;
    r.y = (a.y * c0 + d.y * c1 + e.y * c2 + f.y * c3) * inv;
    r.z = (a.z * c0 + d.z * c1 + e.z * c2 + f.z * c3) * inv;
    r.w = (a.w * c0 + d.w * c1 + e.w * c2 + f.w * c3) * inv;
    *(float4*)(out + (size_t)R * 64 + h0) = r;
}

// ---------------------------------------------------------------------------
extern "C" void kernel_launch(void* const* d_in, const int* in_sizes, int n_in,
                              void* d_out, int out_size, void* d_ws, size_t ws_size,
                              hipStream_t stream)
{
    const float* x  = (const float*)d_in[0];
    const float* Wq = (const float*)d_in[1];
    const float* Wk = (const float*)d_in[2];
    const float* Wv = (const float*)d_in[3];
    float* out = (float*)d_out;

    ushort* ws = (ushort*)d_ws;
    float*  wsf = (float*)d_ws;
    ushort* w_hi = ws + WHI_OFF;
    ushort* w_lo = ws + WLO_OFF;
    ushort* q_hi = ws + QHI_OFF;
    ushort* q_lo = ws + QLO_OFF;
    ushort* k_hi = ws + KHI_OFF;
    ushort* k_lo = ws + KLO_OFF;
    ushort* v_t  = ws + VT_OFF;
    float*  oP   = wsf + OP_OFF;
    float*  mP   = wsf + MP_OFF;
    float*  lP   = wsf + LP_OFF;

    split_w_kernel<<<dim3(576), dim3(256), 0, stream>>>(Wq, Wk, Wv, w_hi, w_lo);
    proj_kernel<<<dim3(512), dim3(256), 0, stream>>>(x, w_hi, w_lo,
                                                     q_hi, q_lo, k_hi, k_lo, v_t);
    attn_kernel<<<dim3(512), dim3(256), 0, stream>>>(q_hi, q_lo, k_hi, k_lo, v_t,
                                                     oP, mP, lP);
    merge_kernel<<<dim3(1024), dim3(256), 0, stream>>>(oP, mP, lP, out);
}